// Round 7
// baseline (541.379 us; speedup 1.0000x reference)
//
#include <hip/hip_runtime.h>
#include <hip/hip_bf16.h>

// GraphSAGE forward: N=50000 nodes, E=600000 edges, D=H=128, G=128 graphs.
//   x_pre = rownorm(x)
//   h   = leaky(l2norm(mean_agg(x_pre) @ W1l.T + x_pre @ W1r.T))
//   h1  = leaky([h | x_pre] @ fc1_W.T + fc1_b)
//   h2  = leaky(l2norm(mean_agg(h1) @ W2l.T + h1 @ W2r.T))
//   h3  = leaky([h2 | h1] @ fc2_W.T + fc2_b)
//   out = l2norm(leaky(segpool(h3) @ fc3_W.T + fc3_b))
//
// R6 post-mortem: GEMM at 59.6us was occupancy-starved (391 blocks x 4 waves
// = ~1 wave/SIMD, VALUBusy 40%). This round: 512-thread blocks (8 waves, 2
// blocks/CU co-resident -> 3-4 waves/SIMD) + correct k-group XOR LDS swizzle
// (store col = c ^ ((krow>>3)<<3), 2 lanes/bank = free). Agg: 2-deep unroll.

#define NEG_SLOPE 0.01f
#define L2EPS 1e-12f

// ---------------- preprocess: row-normalize x ----------------
__global__ void k_preprocess(const float* __restrict__ x, float* __restrict__ xp, int N) {
    int node = blockIdx.x * 4 + (threadIdx.x >> 6);
    int lane = threadIdx.x & 63;
    if (node >= N) return;
    float2 v = ((const float2*)x)[(size_t)node * 64 + lane];
    float s = v.x + v.y;
    #pragma unroll
    for (int off = 32; off > 0; off >>= 1) s += __shfl_xor(s, off);
    float rinv = (s == 0.0f) ? 0.0f : 1.0f / s;
    float2 o; o.x = v.x * rinv; o.y = v.y * rinv;
    ((float2*)xp)[(size_t)node * 64 + lane] = o;
}

// ---------------- CSR build ----------------
__global__ void k_deg(const int* __restrict__ ei, int* __restrict__ deg, int E) {
    int e = blockIdx.x * blockDim.x + threadIdx.x;
    if (e >= E) return;
    atomicAdd(&deg[ei[E + e]], 1);
}

// single-block scan, wave-shuffle based: 3 barriers per 1024-chunk
__global__ void k_scan(const int* __restrict__ deg, int* __restrict__ rs,
                       int* __restrict__ cursor, int N) {
    __shared__ int wsum[16];
    __shared__ int carry_s;
    int t = threadIdx.x;
    int lane = t & 63, w = t >> 6;
    if (t == 0) carry_s = 0;
    __syncthreads();
    for (int base = 0; base < N; base += 1024) {
        int i = base + t;
        int v = (i < N) ? deg[i] : 0;
        int s = v;
        #pragma unroll
        for (int off = 1; off < 64; off <<= 1) {
            int u = __shfl_up(s, off);
            if (lane >= off) s += u;
        }
        if (lane == 63) wsum[w] = s;
        __syncthreads();
        if (w == 0) {
            int x = (lane < 16) ? wsum[lane] : 0;
            #pragma unroll
            for (int off = 1; off < 16; off <<= 1) {
                int u = __shfl_up(x, off);
                if (lane >= off) x += u;
            }
            if (lane < 16) wsum[lane] = x;
        }
        __syncthreads();
        int wexcl = (w == 0) ? 0 : wsum[w - 1];
        int excl = carry_s + wexcl + (s - v);
        if (i < N) { rs[i] = excl; cursor[i] = excl; }
        __syncthreads();
        if (t == 0) carry_s += wsum[15];
        __syncthreads();
    }
    if (t == 0) rs[N] = carry_s;
}

__global__ void k_fill(const int* __restrict__ ei, int* __restrict__ cursor,
                       int* __restrict__ csr, int E) {
    int e = blockIdx.x * blockDim.x + threadIdx.x;
    if (e >= E) return;
    int src = ei[e];
    int dst = ei[E + e];
    int pos = atomicAdd(&cursor[dst], 1);
    csr[pos] = src;
}

// ---------------- mean aggregation: 2 edges/half-wave, 2-deep unroll ----------------
// 4 float4 gathers in flight per wave (2 halves x 2-deep).
__global__ void k_agg(const float* __restrict__ feat, const int* __restrict__ csr,
                      const int* __restrict__ rs, float* __restrict__ mean, int N) {
    int node = blockIdx.x * 4 + (threadIdx.x >> 6);
    int lane = threadIdx.x & 63;
    if (node >= N) return;
    int beg = rs[node], end = rs[node + 1];
    int d = end - beg;
    int half = lane >> 5;   // which of 2 interleaved edge streams
    int sub  = lane & 31;   // float4 index within the 128-float row
    const float4* f4 = (const float4*)feat;
    float a0x = 0.f, a0y = 0.f, a0z = 0.f, a0w = 0.f;
    float a1x = 0.f, a1y = 0.f, a1z = 0.f, a1w = 0.f;
    int p = beg + half;
    for (; p + 2 < end; p += 4) {
        int s0 = csr[p];
        int s1 = csr[p + 2];
        float4 v0 = f4[(size_t)s0 * 32 + sub];
        float4 v1 = f4[(size_t)s1 * 32 + sub];
        a0x += v0.x; a0y += v0.y; a0z += v0.z; a0w += v0.w;
        a1x += v1.x; a1y += v1.y; a1z += v1.z; a1w += v1.w;
    }
    if (p < end) {
        int s0 = csr[p];
        float4 v0 = f4[(size_t)s0 * 32 + sub];
        a0x += v0.x; a0y += v0.y; a0z += v0.z; a0w += v0.w;
    }
    a0x += a1x; a0y += a1y; a0z += a1z; a0w += a1w;
    a0x += __shfl_xor(a0x, 32);
    a0y += __shfl_xor(a0y, 32);
    a0z += __shfl_xor(a0z, 32);
    a0w += __shfl_xor(a0w, 32);
    if (half == 0) {
        float inv = (d > 0) ? (1.0f / (float)d) : 0.0f;
        float4 o = make_float4(a0x * inv, a0y * inv, a0z * inv, a0w * inv);
        ((float4*)(mean + (size_t)node * 128))[sub] = o;
    }
}

// ---------------- fused dual-input GEMM: out = act([A1|A2] @ [Wa|Wb].T) ----------------
// BM=128, BN=128, K=256 (8 kb of 32), 512 threads (8 waves), thread tile 8x4.
// Single LDS buffer, reg-staged prefetch (named scalars), k-group XOR swizzle:
//   value at (krow, c) stored at col c ^ ((krow>>3)<<3)  -> stores 2 lanes/bank.
#define LDT 132  // 528 B row stride (multiple of 16)

// load tile kb_ into named staged regs (2 float4 A + 2 float4 W per thread)
#define LOAD_TILE(kb_) do {                                                   \
    const float* Asrc_ = ((kb_) < 4) ? A1 : A2;                               \
    const float* Wsrc_ = ((kb_) < 4) ? Wa : Wb;                               \
    int ldw_  = ((kb_) < 4) ? ldwa : ldwb;                                    \
    int kloc_ = ((kb_) & 3) * 32;                                             \
    int grow_ = i0 + a_r;                                                     \
    if (grow_ < N) {                                                          \
        const float* ap_ = Asrc_ + (size_t)grow_ * 128 + kloc_ + a_kc;        \
        sa0 = *(const float4*)(ap_);  sa1 = *(const float4*)(ap_ + 4);        \
    } else {                                                                  \
        sa0 = make_float4(0.f, 0.f, 0.f, 0.f); sa1 = sa0;                     \
    }                                                                         \
    const float* wp_ = Wsrc_ + (size_t)a_r * ldw_ + kloc_ + a_kc;             \
    sw0 = *(const float4*)(wp_);  sw1 = *(const float4*)(wp_ + 4);            \
} while (0)

#define STORE_TILE() do {                                                     \
    As[a_kc + 0][fsw] = sa0.x; As[a_kc + 1][fsw] = sa0.y;                     \
    As[a_kc + 2][fsw] = sa0.z; As[a_kc + 3][fsw] = sa0.w;                     \
    As[a_kc + 4][fsw] = sa1.x; As[a_kc + 5][fsw] = sa1.y;                     \
    As[a_kc + 6][fsw] = sa1.z; As[a_kc + 7][fsw] = sa1.w;                     \
    Ws[a_kc + 0][fsw] = sw0.x; Ws[a_kc + 1][fsw] = sw0.y;                     \
    Ws[a_kc + 2][fsw] = sw0.z; Ws[a_kc + 3][fsw] = sw0.w;                     \
    Ws[a_kc + 4][fsw] = sw1.x; Ws[a_kc + 5][fsw] = sw1.y;                     \
    Ws[a_kc + 6][fsw] = sw1.z; Ws[a_kc + 7][fsw] = sw1.w;                     \
} while (0)

template <bool L2N, bool BIAS>
__global__ __launch_bounds__(512, 4) void k_gemm2(
    const float* __restrict__ A1, const float* __restrict__ A2,
    const float* __restrict__ Wa, int ldwa,
    const float* __restrict__ Wb, int ldwb,
    const float* __restrict__ bias,
    float* __restrict__ out, int N)
{
    __shared__ float As[32][LDT];
    __shared__ float Ws[32][LDT];
    int t = threadIdx.x;
    int tx = t & 31;          // col group: output cols tx*4..+3
    int ty = t >> 5;          // row group: output rows ty*8..+7
    int i0 = blockIdx.x * 128;

    float acc[8][4];
    #pragma unroll
    for (int j = 0; j < 8; ++j)
        #pragma unroll
        for (int i = 0; i < 4; ++i) acc[j][i] = 0.f;

    int a_r  = t >> 2;           // 0..127: A row / W feature row
    int a_m  = t & 3;            // k-chunk selector
    int a_kc = a_m * 8;          // 8 consecutive k per thread
    int fsw  = a_r ^ (a_m << 3); // swizzled LDS store column

    float4 sa0, sa1, sw0, sw1;

    LOAD_TILE(0);

    for (int kb = 0; kb < 8; ++kb) {
        __syncthreads();   // previous tile fully consumed
        STORE_TILE();
        __syncthreads();
        if (kb < 7) LOAD_TILE(kb + 1);  // latency hides under compute below

        #pragma unroll
        for (int k = 0; k < 32; ++k) {
            int xk = (k >> 3) << 3;   // k-group XOR (matches store swizzle)
            float4 a0 = *(const float4*)&As[k][(ty * 8) ^ xk];
            float4 a1 = *(const float4*)&As[k][(ty * 8 + 4) ^ xk];
            float4 w0 = *(const float4*)&Ws[k][(tx * 4) ^ xk];
            float ar[8] = {a0.x, a0.y, a0.z, a0.w, a1.x, a1.y, a1.z, a1.w};
            float wr[4] = {w0.x, w0.y, w0.z, w0.w};
            #pragma unroll
            for (int j = 0; j < 8; ++j)
                #pragma unroll
                for (int i = 0; i < 4; ++i) acc[j][i] += ar[j] * wr[i];
        }
    }

    // epilogue: row's 128 cols live on lanes (tx) 0..31 of the same 32-lane half
    float scale[8];
    if (L2N) {
        #pragma unroll
        for (int j = 0; j < 8; ++j) {
            float s = acc[j][0]*acc[j][0] + acc[j][1]*acc[j][1]
                    + acc[j][2]*acc[j][2] + acc[j][3]*acc[j][3];
            #pragma unroll
            for (int off = 1; off < 32; off <<= 1) s += __shfl_xor(s, off);
            scale[j] = 1.0f / fmaxf(sqrtf(s), L2EPS);
        }
    }
    float b4[4];
    if (BIAS) {
        #pragma unroll
        for (int i = 0; i < 4; ++i) b4[i] = bias[tx * 4 + i];
    }
    #pragma unroll
    for (int j = 0; j < 8; ++j) {
        int row = i0 + ty * 8 + j;
        if (row >= N) continue;
        float4 v; float* vp = (float*)&v;
        #pragma unroll
        for (int i = 0; i < 4; ++i) {
            float xv = acc[j][i];
            if (L2N) xv *= scale[j];
            if (BIAS) xv += b4[i];
            vp[i] = (xv >= 0.f) ? xv : NEG_SLOPE * xv;
        }
        *(float4*)(out + (size_t)row * 128 + tx * 4) = v;
    }
}

// ---------------- pool: chunked partial sums over sorted batch ----------------
#define POOL_ROWS 128
__global__ void k_pool(const float* __restrict__ h3, const int* __restrict__ batch,
                       float* __restrict__ pooled, int N) {
    int f = threadIdx.x;  // 0..127
    int base = blockIdx.x * POOL_ROWS;
    if (base >= N) return;
    int end = min(base + POOL_ROWS, N);
    float acc = 0.f;
    int cur = batch[base];
    for (int i = base; i < end; ++i) {
        int g = batch[i];
        if (g != cur) {
            atomicAdd(&pooled[cur * 128 + f], acc);
            acc = 0.f; cur = g;
        }
        acc += h3[(size_t)i * 128 + f];
    }
    atomicAdd(&pooled[cur * 128 + f], acc);
}

__global__ void k_fc3(const float* __restrict__ pooled, const float* __restrict__ W,
                      const float* __restrict__ b, float* __restrict__ out) {
    int g = blockIdx.x, f = threadIdx.x;
    __shared__ float prow[128];
    __shared__ float red[128];
    prow[f] = pooled[g * 128 + f];
    __syncthreads();
    float acc = b[f];
    #pragma unroll 8
    for (int k = 0; k < 128; ++k) acc += prow[k] * W[f * 128 + k];
    float v = (acc >= 0.f) ? acc : NEG_SLOPE * acc;
    red[f] = v * v;
    __syncthreads();
    for (int o = 64; o > 0; o >>= 1) {
        if (f < o) red[f] += red[f + o];
        __syncthreads();
    }
    float sc = 1.0f / fmaxf(sqrtf(red[0]), L2EPS);
    out[g * 128 + f] = v * sc;
}

// ---------------- launch ----------------
extern "C" void kernel_launch(void* const* d_in, const int* in_sizes, int n_in,
                              void* d_out, int out_size, void* d_ws, size_t ws_size,
                              hipStream_t stream) {
    const float* x    = (const float*)d_in[0];
    const int*   ei   = (const int*)d_in[1];
    const int*   batch= (const int*)d_in[2];
    const float* W1l  = (const float*)d_in[3];
    const float* W1r  = (const float*)d_in[4];
    const float* W2l  = (const float*)d_in[5];
    const float* W2r  = (const float*)d_in[6];
    const float* fc1W = (const float*)d_in[7];
    const float* fc1b = (const float*)d_in[8];
    const float* fc2W = (const float*)d_in[9];
    const float* fc2b = (const float*)d_in[10];
    const float* fc3W = (const float*)d_in[11];
    const float* fc3b = (const float*)d_in[12];

    int N = in_sizes[0] / 128;
    int E = in_sizes[1] / 2;
    int G = out_size / 128;
    float* out = (float*)d_out;

    char* ws = (char*)d_ws;
    size_t off = 0;
    auto alloc = [&](size_t bytes) -> void* {
        void* p = ws + off;
        off = (off + bytes + 255) & ~(size_t)255;
        return p;
    };
    float* xp     = (float*)alloc((size_t)N * 128 * 4);  // x_pre, later reused as h3
    float* mean   = (float*)alloc((size_t)N * 128 * 4);
    float* h      = (float*)alloc((size_t)N * 128 * 4);  // h, later h2
    float* h1     = (float*)alloc((size_t)N * 128 * 4);
    float* pooled = (float*)alloc((size_t)G * 128 * 4);
    int* deg      = (int*)alloc((size_t)N * 4);
    int* rs       = (int*)alloc((size_t)(N + 1) * 4);
    int* cursor   = (int*)alloc((size_t)N * 4);
    int* csr      = (int*)alloc((size_t)E * 4);
    (void)ws_size; (void)n_in;

    hipMemsetAsync(deg, 0, (size_t)N * 4, stream);
    hipMemsetAsync(pooled, 0, (size_t)G * 128 * 4, stream);

    k_preprocess<<<(N + 3) / 4, 256, 0, stream>>>(x, xp, N);
    k_deg<<<(E + 255) / 256, 256, 0, stream>>>(ei, deg, E);
    k_scan<<<1, 1024, 0, stream>>>(deg, rs, cursor, N);
    k_fill<<<(E + 255) / 256, 256, 0, stream>>>(ei, cursor, csr, E);

    int gb = (N + 127) / 128;
    // conv1 + fc1
    k_agg<<<(N + 3) / 4, 256, 0, stream>>>(xp, csr, rs, mean, N);
    k_gemm2<true, false><<<gb, 512, 0, stream>>>(
        mean, xp, W1l, 128, W1r, 128, nullptr, h, N);
    k_gemm2<false, true><<<gb, 512, 0, stream>>>(
        h, xp, fc1W, 256, fc1W + 128, 256, fc1b, h1, N);

    // conv2 + fc2 (h2 -> h buffer, h3 -> xp buffer)
    k_agg<<<(N + 3) / 4, 256, 0, stream>>>(h1, csr, rs, mean, N);
    k_gemm2<true, false><<<gb, 512, 0, stream>>>(
        mean, h1, W2l, 128, W2r, 128, nullptr, h, N);
    k_gemm2<false, true><<<gb, 512, 0, stream>>>(
        h, h1, fc2W, 256, fc2W + 128, 256, fc2b, xp, N);

    // pool + head
    k_pool<<<(N + POOL_ROWS - 1) / POOL_ROWS, 128, 0, stream>>>(xp, batch, pooled, N);
    k_fc3<<<G, 128, 0, stream>>>(pooled, fc3W, fc3b, out);
}

// Round 8
// 378.196 us; speedup vs baseline: 1.4315x; 1.4315x over previous
//
#include <hip/hip_runtime.h>
#include <hip/hip_bf16.h>

// GraphSAGE forward: N=50000 nodes, E=600000 edges, D=H=128, G=128 graphs.
// R7: bf16 MFMA GEMM (v_mfma_f32_16x16x32_bf16) + bf16 intermediates.
//   - f32 VALU GEMM was capped at ~58us (MfmaUtil 0, load-imbalanced FMA floor).
//   - A/B operands: row/col = lane&15, k-chunk on lane>>4; A and B share the
//     same k mapping so sum over k is invariant to the exact k permutation.
//   - C/D map (m89-verified): col = lane&15, row = (lane>>4)*4 + reg.
//   - LDS: two K=16 half-tiles, row stride 40 bf16 (80 B) -> b64 fragment
//     reads land exactly 4 phases (conflict-free), b128 staging writes aligned.

#define NEG_SLOPE 0.01f
#define L2EPS 1e-12f

typedef unsigned short u16;
typedef short bf16x8 __attribute__((ext_vector_type(8)));
typedef short s16x4  __attribute__((ext_vector_type(4)));
typedef float f32x4  __attribute__((ext_vector_type(4)));

__device__ __forceinline__ float bf_lo(unsigned int u) {
    union { unsigned int i; float f; } v; v.i = u << 16; return v.f;
}
__device__ __forceinline__ float bf_hi(unsigned int u) {
    union { unsigned int i; float f; } v; v.i = u & 0xffff0000u; return v.f;
}
__device__ __forceinline__ u16 f2bf(float f) {
    union { float f; unsigned int i; } v; v.f = f;
    unsigned int r = v.i + 0x7fffu + ((v.i >> 16) & 1u);
    return (u16)(r >> 16);
}
__device__ __forceinline__ float bf2f(u16 u) {
    union { unsigned int i; float f; } v; v.i = ((unsigned int)u) << 16; return v.f;
}

// ---------------- preprocess: row-normalize x, write bf16 ----------------
__global__ void k_preprocess(const float* __restrict__ x, u16* __restrict__ xp, int N) {
    int node = blockIdx.x * 4 + (threadIdx.x >> 6);
    int lane = threadIdx.x & 63;
    if (node >= N) return;
    float2 v = ((const float2*)x)[(size_t)node * 64 + lane];
    float s = v.x + v.y;
    #pragma unroll
    for (int off = 32; off > 0; off >>= 1) s += __shfl_xor(s, off);
    float rinv = (s == 0.0f) ? 0.0f : 1.0f / s;
    unsigned int lo = f2bf(v.x * rinv), hi = f2bf(v.y * rinv);
    ((unsigned int*)xp)[(size_t)node * 64 + lane] = lo | (hi << 16);
}

// ---------------- CSR build ----------------
__global__ void k_deg(const int* __restrict__ ei, int* __restrict__ deg, int E) {
    int e = blockIdx.x * blockDim.x + threadIdx.x;
    if (e >= E) return;
    atomicAdd(&deg[ei[E + e]], 1);
}

__global__ void k_scan(const int* __restrict__ deg, int* __restrict__ rs,
                       int* __restrict__ cursor, int N) {
    __shared__ int wsum[16];
    __shared__ int carry_s;
    int t = threadIdx.x;
    int lane = t & 63, w = t >> 6;
    if (t == 0) carry_s = 0;
    __syncthreads();
    for (int base = 0; base < N; base += 1024) {
        int i = base + t;
        int v = (i < N) ? deg[i] : 0;
        int s = v;
        #pragma unroll
        for (int off = 1; off < 64; off <<= 1) {
            int u = __shfl_up(s, off);
            if (lane >= off) s += u;
        }
        if (lane == 63) wsum[w] = s;
        __syncthreads();
        if (w == 0) {
            int x = (lane < 16) ? wsum[lane] : 0;
            #pragma unroll
            for (int off = 1; off < 16; off <<= 1) {
                int u = __shfl_up(x, off);
                if (lane >= off) x += u;
            }
            if (lane < 16) wsum[lane] = x;
        }
        __syncthreads();
        int wexcl = (w == 0) ? 0 : wsum[w - 1];
        int excl = carry_s + wexcl + (s - v);
        if (i < N) { rs[i] = excl; cursor[i] = excl; }
        __syncthreads();
        if (t == 0) carry_s += wsum[15];
        __syncthreads();
    }
    if (t == 0) rs[N] = carry_s;
}

__global__ void k_fill(const int* __restrict__ ei, int* __restrict__ cursor,
                       int* __restrict__ csr, int E) {
    int e = blockIdx.x * blockDim.x + threadIdx.x;
    if (e >= E) return;
    int src = ei[e];
    int dst = ei[E + e];
    int pos = atomicAdd(&cursor[dst], 1);
    csr[pos] = src;
}

// ---------------- mean aggregation: bf16 gathers, f32 accumulate ----------------
// 2 edge streams x 2-deep unroll = 4 gathers in flight; 8 B/lane per edge row.
__global__ void k_agg(const u16* __restrict__ feat, const int* __restrict__ csr,
                      const int* __restrict__ rs, u16* __restrict__ mean, int N) {
    int node = blockIdx.x * 4 + (threadIdx.x >> 6);
    int lane = threadIdx.x & 63;
    if (node >= N) return;
    int beg = rs[node], end = rs[node + 1];
    int d = end - beg;
    int half = lane >> 5;
    int sub  = lane & 31;   // uint2 (4 bf16) chunk within the 128-elem row
    const uint2* fp = (const uint2*)feat;
    float a00 = 0.f, a01 = 0.f, a02 = 0.f, a03 = 0.f;
    float a10 = 0.f, a11 = 0.f, a12 = 0.f, a13 = 0.f;
    int p = beg + half;
    for (; p + 2 < end; p += 4) {
        int s0 = csr[p], s1 = csr[p + 2];
        uint2 v0 = fp[(size_t)s0 * 32 + sub];
        uint2 v1 = fp[(size_t)s1 * 32 + sub];
        a00 += bf_lo(v0.x); a01 += bf_hi(v0.x); a02 += bf_lo(v0.y); a03 += bf_hi(v0.y);
        a10 += bf_lo(v1.x); a11 += bf_hi(v1.x); a12 += bf_lo(v1.y); a13 += bf_hi(v1.y);
    }
    if (p < end) {
        int s0 = csr[p];
        uint2 v0 = fp[(size_t)s0 * 32 + sub];
        a00 += bf_lo(v0.x); a01 += bf_hi(v0.x); a02 += bf_lo(v0.y); a03 += bf_hi(v0.y);
    }
    a00 += a10; a01 += a11; a02 += a12; a03 += a13;
    a00 += __shfl_xor(a00, 32);
    a01 += __shfl_xor(a01, 32);
    a02 += __shfl_xor(a02, 32);
    a03 += __shfl_xor(a03, 32);
    if (half == 0) {
        float inv = (d > 0) ? (1.0f / (float)d) : 0.0f;
        uint2 o;
        o.x = (unsigned int)f2bf(a00 * inv) | ((unsigned int)f2bf(a01 * inv) << 16);
        o.y = (unsigned int)f2bf(a02 * inv) | ((unsigned int)f2bf(a03 * inv) << 16);
        ((uint2*)mean)[(size_t)node * 32 + sub] = o;
    }
}

// ---------------- MFMA GEMM: out = act([A1|A2] @ [Wa|Wb].T), bf16 in/out ----------------
// BM=64, BN=128 (full width), K=256 as 8 kb of 32. 256 threads = 4 waves;
// wave w owns rows w*16..w*16+15, all 128 cols = 8 MFMA fragments.
#define PK(lo_, hi_) ((unsigned int)f2bf(lo_) | ((unsigned int)f2bf(hi_) << 16))

#define LOAD_TILE(kb_) do {                                                    \
    const u16*   Asrc_ = ((kb_) < 4) ? A1 : A2;                                \
    const float* Wsrc_ = ((kb_) < 4) ? Wa : Wb;                                \
    int ldw_  = ((kb_) < 4) ? ldwa : ldwb;                                     \
    int kloc_ = ((kb_) & 3) * 32;                                              \
    int grow_ = i0 + a_row;                                                    \
    if (grow_ < N) sA = *(const uint4*)(Asrc_ + (size_t)grow_ * 128 + kloc_ + a_q * 8); \
    else           sA = make_uint4(0u, 0u, 0u, 0u);                            \
    const float* wp_ = Wsrc_ + (size_t)w_row * ldw_ + kloc_ + w_half * 16;     \
    sw0 = *(const float4*)(wp_);      sw1 = *(const float4*)(wp_ + 4);         \
    sw2 = *(const float4*)(wp_ + 8);  sw3 = *(const float4*)(wp_ + 12);        \
} while (0)

#define STORE_TILE() do {                                                      \
    *(uint4*)&Al[a_half][a_row][a_col0] = sA;                                  \
    uint4 wv_;                                                                 \
    wv_.x = PK(sw0.x, sw0.y); wv_.y = PK(sw0.z, sw0.w);                        \
    wv_.z = PK(sw1.x, sw1.y); wv_.w = PK(sw1.z, sw1.w);                        \
    *(uint4*)&Wl[w_half][w_row][0] = wv_;                                      \
    wv_.x = PK(sw2.x, sw2.y); wv_.y = PK(sw2.z, sw2.w);                        \
    wv_.z = PK(sw3.x, sw3.y); wv_.w = PK(sw3.z, sw3.w);                        \
    *(uint4*)&Wl[w_half][w_row][8] = wv_;                                      \
} while (0)

template <bool L2N, bool BIAS>
__global__ __launch_bounds__(256, 4) void k_gemm2(
    const u16* __restrict__ A1, const u16* __restrict__ A2,
    const float* __restrict__ Wa, int ldwa,
    const float* __restrict__ Wb, int ldwb,
    const float* __restrict__ bias,
    u16* __restrict__ out, int N)
{
    // [k-half][row][40] bf16; 80 B row stride: 16B-aligned writes, b64 frag
    // reads hit each bank exactly 4x (minimum phases) -> conflict-free.
    __shared__ u16 Al[2][64][40];
    __shared__ u16 Wl[2][128][40];
    int t = threadIdx.x;
    int i0 = blockIdx.x * 64;

    // staging map
    int a_row  = t >> 2;            // 0..63
    int a_q    = t & 3;             // which 8-k chunk
    int a_half = a_q >> 1;          // k-half (0: k<16, 1: k>=16)
    int a_col0 = (a_q & 1) * 8;     // col within half-tile
    int w_row  = t >> 1;            // 0..127 (output feature)
    int w_half = t & 1;             // k-half

    // compute map
    int c16 = t & 15;               // fragment col / A row within wave tile
    int g   = (t >> 4) & 3;         // k-chunk group within lane
    int wid = t >> 6;               // wave id: rows wid*16..+15
    int ar  = wid * 16 + c16;       // A row for this lane's fragment
    int g4  = g * 4;                // bf16 offset of this lane's 4-k chunk

    f32x4 acc[8];
    #pragma unroll
    for (int cb = 0; cb < 8; ++cb) acc[cb] = (f32x4){0.f, 0.f, 0.f, 0.f};

    uint4 sA;
    float4 sw0, sw1, sw2, sw3;

    LOAD_TILE(0);

    union U8 { bf16x8 v; s16x4 h[2]; };

    for (int kb = 0; kb < 8; ++kb) {
        __syncthreads();   // previous tile fully consumed
        STORE_TILE();
        __syncthreads();
        if (kb < 7) LOAD_TILE(kb + 1);  // hide under MFMA below

        U8 af;
        af.h[0] = *(const s16x4*)&Al[0][ar][g4];
        af.h[1] = *(const s16x4*)&Al[1][ar][g4];
        #pragma unroll
        for (int cb = 0; cb < 8; ++cb) {
            U8 bfr;
            int wr = cb * 16 + c16;
            bfr.h[0] = *(const s16x4*)&Wl[0][wr][g4];
            bfr.h[1] = *(const s16x4*)&Wl[1][wr][g4];
            acc[cb] = __builtin_amdgcn_mfma_f32_16x16x32_bf16(af.v, bfr.v, acc[cb], 0, 0, 0);
        }
    }

    // epilogue. D map: col = lane&15 (within cb), row = wid*16 + g*4 + reg.
    float scs[4];
    if (L2N) {
        float s0 = 0.f, s1 = 0.f, s2 = 0.f, s3 = 0.f;
        #pragma unroll
        for (int cb = 0; cb < 8; ++cb) {
            s0 += acc[cb][0] * acc[cb][0];
            s1 += acc[cb][1] * acc[cb][1];
            s2 += acc[cb][2] * acc[cb][2];
            s3 += acc[cb][3] * acc[cb][3];
        }
        #pragma unroll
        for (int off = 1; off < 16; off <<= 1) {  // reduce across the 16-lane row group
            s0 += __shfl_xor(s0, off);
            s1 += __shfl_xor(s1, off);
            s2 += __shfl_xor(s2, off);
            s3 += __shfl_xor(s3, off);
        }
        scs[0] = 1.0f / fmaxf(sqrtf(s0), L2EPS);
        scs[1] = 1.0f / fmaxf(sqrtf(s1), L2EPS);
        scs[2] = 1.0f / fmaxf(sqrtf(s2), L2EPS);
        scs[3] = 1.0f / fmaxf(sqrtf(s3), L2EPS);
    }
    float bv[8];
    if (BIAS) {
        #pragma unroll
        for (int cb = 0; cb < 8; ++cb) bv[cb] = bias[cb * 16 + c16];
    }
    int rbase = i0 + wid * 16 + g * 4;
    #pragma unroll
    for (int reg = 0; reg < 4; ++reg) {
        int grow = rbase + reg;
        if (grow >= N) continue;
        #pragma unroll
        for (int cb = 0; cb < 8; ++cb) {
            float xv = acc[cb][reg];
            if (L2N) xv *= scs[reg];
            if (BIAS) xv += bv[cb];
            float r = (xv >= 0.f) ? xv : NEG_SLOPE * xv;
            out[(size_t)grow * 128 + cb * 16 + c16] = f2bf(r);
        }
    }
}

// ---------------- pool: chunked partial sums over sorted batch (bf16 in) ----------------
#define POOL_ROWS 128
__global__ void k_pool(const u16* __restrict__ h3, const int* __restrict__ batch,
                       float* __restrict__ pooled, int N) {
    int f = threadIdx.x;  // 0..127
    int base = blockIdx.x * POOL_ROWS;
    if (base >= N) return;
    int end = min(base + POOL_ROWS, N);
    float acc = 0.f;
    int cur = batch[base];
    for (int i = base; i < end; ++i) {
        int g = batch[i];
        if (g != cur) {
            atomicAdd(&pooled[cur * 128 + f], acc);
            acc = 0.f; cur = g;
        }
        acc += bf2f(h3[(size_t)i * 128 + f]);
    }
    atomicAdd(&pooled[cur * 128 + f], acc);
}

__global__ void k_fc3(const float* __restrict__ pooled, const float* __restrict__ W,
                      const float* __restrict__ b, float* __restrict__ out) {
    int g = blockIdx.x, f = threadIdx.x;
    __shared__ float prow[128];
    __shared__ float red[128];
    prow[f] = pooled[g * 128 + f];
    __syncthreads();
    float acc = b[f];
    #pragma unroll 8
    for (int k = 0; k < 128; ++k) acc += prow[k] * W[f * 128 + k];
    float v = (acc >= 0.f) ? acc : NEG_SLOPE * acc;
    red[f] = v * v;
    __syncthreads();
    for (int o = 64; o > 0; o >>= 1) {
        if (f < o) red[f] += red[f + o];
        __syncthreads();
    }
    float sc = 1.0f / fmaxf(sqrtf(red[0]), L2EPS);
    out[g * 128 + f] = v * sc;
}

// ---------------- launch ----------------
extern "C" void kernel_launch(void* const* d_in, const int* in_sizes, int n_in,
                              void* d_out, int out_size, void* d_ws, size_t ws_size,
                              hipStream_t stream) {
    const float* x    = (const float*)d_in[0];
    const int*   ei   = (const int*)d_in[1];
    const int*   batch= (const int*)d_in[2];
    const float* W1l  = (const float*)d_in[3];
    const float* W1r  = (const float*)d_in[4];
    const float* W2l  = (const float*)d_in[5];
    const float* W2r  = (const float*)d_in[6];
    const float* fc1W = (const float*)d_in[7];
    const float* fc1b = (const float*)d_in[8];
    const float* fc2W = (const float*)d_in[9];
    const float* fc2b = (const float*)d_in[10];
    const float* fc3W = (const float*)d_in[11];
    const float* fc3b = (const float*)d_in[12];

    int N = in_sizes[0] / 128;
    int E = in_sizes[1] / 2;
    int G = out_size / 128;
    float* out = (float*)d_out;

    char* ws = (char*)d_ws;
    size_t off = 0;
    auto alloc = [&](size_t bytes) -> void* {
        void* p = ws + off;
        off = (off + bytes + 255) & ~(size_t)255;
        return p;
    };
    u16* xp     = (u16*)alloc((size_t)N * 128 * 2);  // x_pre, later reused as h3
    u16* mean   = (u16*)alloc((size_t)N * 128 * 2);
    u16* h      = (u16*)alloc((size_t)N * 128 * 2);  // h, later h2
    u16* h1     = (u16*)alloc((size_t)N * 128 * 2);
    float* pooled = (float*)alloc((size_t)G * 128 * 4);
    int* deg    = (int*)alloc((size_t)N * 4);
    int* rs     = (int*)alloc((size_t)(N + 1) * 4);
    int* cursor = (int*)alloc((size_t)N * 4);
    int* csr    = (int*)alloc((size_t)E * 4);
    (void)ws_size; (void)n_in;

    hipMemsetAsync(deg, 0, (size_t)N * 4, stream);
    hipMemsetAsync(pooled, 0, (size_t)G * 128 * 4, stream);

    k_preprocess<<<(N + 3) / 4, 256, 0, stream>>>(x, xp, N);
    k_deg<<<(E + 255) / 256, 256, 0, stream>>>(ei, deg, E);
    k_scan<<<1, 1024, 0, stream>>>(deg, rs, cursor, N);
    k_fill<<<(E + 255) / 256, 256, 0, stream>>>(ei, cursor, csr, E);

    int gb = (N + 63) / 64;
    // conv1 + fc1
    k_agg<<<(N + 3) / 4, 256, 0, stream>>>(xp, csr, rs, mean, N);
    k_gemm2<true, false><<<gb, 256, 0, stream>>>(
        mean, xp, W1l, 128, W1r, 128, nullptr, h, N);
    k_gemm2<false, true><<<gb, 256, 0, stream>>>(
        h, xp, fc1W, 256, fc1W + 128, 256, fc1b, h1, N);

    // conv2 + fc2 (h2 -> h buffer, h3 -> xp buffer)
    k_agg<<<(N + 3) / 4, 256, 0, stream>>>(h1, csr, rs, mean, N);
    k_gemm2<true, false><<<gb, 256, 0, stream>>>(
        mean, h1, W2l, 128, W2r, 128, nullptr, h, N);
    k_gemm2<false, true><<<gb, 256, 0, stream>>>(
        h, h1, fc2W, 256, fc2W + 128, 256, fc2b, xp, N);

    // pool + head
    k_pool<<<(N + POOL_ROWS - 1) / POOL_ROWS, 128, 0, stream>>>(xp, batch, pooled, N);
    k_fc3<<<G, 128, 0, stream>>>(pooled, fc3W, fc3b, out);
}

// Round 10
// 327.461 us; speedup vs baseline: 1.6533x; 1.1549x over previous
//
#include <hip/hip_runtime.h>
#include <hip/hip_bf16.h>

// GraphSAGE forward: N=50000 nodes, E=600000 edges, D=H=128, G=128 graphs.
// R8: bf16 MFMA GEMM + bf16 intermediates (378us, absmax 2e-3).
// R9: multi-block scan (was 50us single-block latency) + 4-stream agg gathers.

#define NEG_SLOPE 0.01f
#define L2EPS 1e-12f

typedef unsigned short u16;
typedef short bf16x8 __attribute__((ext_vector_type(8)));
typedef short s16x4  __attribute__((ext_vector_type(4)));
typedef float f32x4  __attribute__((ext_vector_type(4)));

__device__ __forceinline__ float bf_lo(unsigned int u) {
    union { unsigned int i; float f; } v; v.i = u << 16; return v.f;
}
__device__ __forceinline__ float bf_hi(unsigned int u) {
    union { unsigned int i; float f; } v; v.i = u & 0xffff0000u; return v.f;
}
__device__ __forceinline__ u16 f2bf(float f) {
    union { float f; unsigned int i; } v; v.f = f;
    unsigned int r = v.i + 0x7fffu + ((v.i >> 16) & 1u);
    return (u16)(r >> 16);
}
__device__ __forceinline__ float bf2f(u16 u) {
    union { unsigned int i; float f; } v; v.i = ((unsigned int)u) << 16; return v.f;
}

// ---------------- preprocess: row-normalize x, write bf16 ----------------
__global__ void k_preprocess(const float* __restrict__ x, u16* __restrict__ xp, int N) {
    int node = blockIdx.x * 4 + (threadIdx.x >> 6);
    int lane = threadIdx.x & 63;
    if (node >= N) return;
    float2 v = ((const float2*)x)[(size_t)node * 64 + lane];
    float s = v.x + v.y;
    #pragma unroll
    for (int off = 32; off > 0; off >>= 1) s += __shfl_xor(s, off);
    float rinv = (s == 0.0f) ? 0.0f : 1.0f / s;
    unsigned int lo = f2bf(v.x * rinv), hi = f2bf(v.y * rinv);
    ((unsigned int*)xp)[(size_t)node * 64 + lane] = lo | (hi << 16);
}

// ---------------- CSR build ----------------
__global__ void k_deg(const int* __restrict__ ei, int* __restrict__ deg, int E) {
    int e = blockIdx.x * blockDim.x + threadIdx.x;
    if (e >= E) return;
    atomicAdd(&deg[ei[E + e]], 1);
}

// multi-block scan, stage 1: block-local exclusive scan + block totals
__global__ void k_scan_part(const int* __restrict__ deg, int* __restrict__ rs,
                            int* __restrict__ bsum, int N) {
    __shared__ int wsum[16];
    int t = threadIdx.x;
    int lane = t & 63, w = t >> 6;
    int i = blockIdx.x * 1024 + t;
    int v = (i < N) ? deg[i] : 0;
    int s = v;
    #pragma unroll
    for (int off = 1; off < 64; off <<= 1) {
        int u = __shfl_up(s, off);
        if (lane >= off) s += u;
    }
    if (lane == 63) wsum[w] = s;
    __syncthreads();
    if (w == 0) {
        int x = (lane < 16) ? wsum[lane] : 0;
        #pragma unroll
        for (int off = 1; off < 16; off <<= 1) {
            int u = __shfl_up(x, off);
            if (lane >= off) x += u;
        }
        if (lane < 16) wsum[lane] = x;
    }
    __syncthreads();
    int wexcl = (w == 0) ? 0 : wsum[w - 1];
    if (i < N) rs[i] = wexcl + s - v;
    if (t == 1023) bsum[blockIdx.x] = wexcl + s;  // block total
}

// stage 2: one wave scans block totals (nb <= 64), writes rs[N]
__global__ void k_scan_bsum(int* __restrict__ bsum, int* __restrict__ rs,
                            int nb, int N) {
    int lane = threadIdx.x;
    int v = (lane < nb) ? bsum[lane] : 0;
    int s = v;
    #pragma unroll
    for (int off = 1; off < 64; off <<= 1) {
        int u = __shfl_up(s, off);
        if (lane >= off) s += u;
    }
    if (lane < nb) bsum[lane] = s - v;  // exclusive
    if (lane == nb - 1) rs[N] = s;      // grand total = E
}

// stage 3: add block offsets, emit cursor copy
__global__ void k_scan_add(int* __restrict__ rs, int* __restrict__ cursor,
                           const int* __restrict__ bsum, int N) {
    int i = blockIdx.x * 256 + threadIdx.x;
    if (i >= N) return;
    int v = rs[i] + bsum[i >> 10];
    rs[i] = v;
    cursor[i] = v;
}

__global__ void k_fill(const int* __restrict__ ei, int* __restrict__ cursor,
                       int* __restrict__ csr, int E) {
    int e = blockIdx.x * blockDim.x + threadIdx.x;
    if (e >= E) return;
    int src = ei[e];
    int dst = ei[E + e];
    int pos = atomicAdd(&cursor[dst], 1);
    csr[pos] = src;
}

// ---------------- mean aggregation: 4 edge streams x 2-deep, uint4 gathers ----------------
// 16-lane groups each gather a full 256 B row; 8 loads in flight per wave.
__global__ void k_agg(const u16* __restrict__ feat, const int* __restrict__ csr,
                      const int* __restrict__ rs, u16* __restrict__ mean, int N) {
    int node = blockIdx.x * 4 + (threadIdx.x >> 6);
    int lane = threadIdx.x & 63;
    if (node >= N) return;
    int beg = rs[node], end = rs[node + 1];
    int d = end - beg;
    int q   = lane >> 4;    // edge stream 0..3
    int sub = lane & 15;    // uint4 chunk within the 128-bf16 row
    const uint4* fp = (const uint4*)feat;
    float4 aA0 = {0.f,0.f,0.f,0.f}, aB0 = {0.f,0.f,0.f,0.f};
    float4 aA1 = {0.f,0.f,0.f,0.f}, aB1 = {0.f,0.f,0.f,0.f};
    int p = beg + q;
    for (; p + 4 < end; p += 8) {
        int s0 = csr[p], s1 = csr[p + 4];
        uint4 v0 = fp[(size_t)s0 * 16 + sub];
        uint4 v1 = fp[(size_t)s1 * 16 + sub];
        aA0.x += bf_lo(v0.x); aA0.y += bf_hi(v0.x);
        aA0.z += bf_lo(v0.y); aA0.w += bf_hi(v0.y);
        aB0.x += bf_lo(v0.z); aB0.y += bf_hi(v0.z);
        aB0.z += bf_lo(v0.w); aB0.w += bf_hi(v0.w);
        aA1.x += bf_lo(v1.x); aA1.y += bf_hi(v1.x);
        aA1.z += bf_lo(v1.y); aA1.w += bf_hi(v1.y);
        aB1.x += bf_lo(v1.z); aB1.y += bf_hi(v1.z);
        aB1.z += bf_lo(v1.w); aB1.w += bf_hi(v1.w);
    }
    if (p < end) {
        int s0 = csr[p];
        uint4 v0 = fp[(size_t)s0 * 16 + sub];
        aA0.x += bf_lo(v0.x); aA0.y += bf_hi(v0.x);
        aA0.z += bf_lo(v0.y); aA0.w += bf_hi(v0.y);
        aB0.x += bf_lo(v0.z); aB0.y += bf_hi(v0.z);
        aB0.z += bf_lo(v0.w); aB0.w += bf_hi(v0.w);
    }
    aA0.x += aA1.x; aA0.y += aA1.y; aA0.z += aA1.z; aA0.w += aA1.w;
    aB0.x += aB1.x; aB0.y += aB1.y; aB0.z += aB1.z; aB0.w += aB1.w;
    #pragma unroll
    for (int off = 16; off <= 32; off <<= 1) {
        aA0.x += __shfl_xor(aA0.x, off); aA0.y += __shfl_xor(aA0.y, off);
        aA0.z += __shfl_xor(aA0.z, off); aA0.w += __shfl_xor(aA0.w, off);
        aB0.x += __shfl_xor(aB0.x, off); aB0.y += __shfl_xor(aB0.y, off);
        aB0.z += __shfl_xor(aB0.z, off); aB0.w += __shfl_xor(aB0.w, off);
    }
    if (q == 0) {
        float inv = (d > 0) ? (1.0f / (float)d) : 0.0f;
        uint4 o;
        o.x = (unsigned int)f2bf(aA0.x * inv) | ((unsigned int)f2bf(aA0.y * inv) << 16);
        o.y = (unsigned int)f2bf(aA0.z * inv) | ((unsigned int)f2bf(aA0.w * inv) << 16);
        o.z = (unsigned int)f2bf(aB0.x * inv) | ((unsigned int)f2bf(aB0.y * inv) << 16);
        o.w = (unsigned int)f2bf(aB0.z * inv) | ((unsigned int)f2bf(aB0.w * inv) << 16);
        ((uint4*)mean)[(size_t)node * 16 + sub] = o;
    }
}

// ---------------- MFMA GEMM: out = act([A1|A2] @ [Wa|Wb].T), bf16 in/out ----------------
// BM=64, BN=128, K=256 as 8 kb of 32. 256 threads = 4 waves;
// wave w owns rows w*16..w*16+15, all 128 cols = 8 MFMA fragments.
#define PK(lo_, hi_) ((unsigned int)f2bf(lo_) | ((unsigned int)f2bf(hi_) << 16))

#define LOAD_TILE(kb_) do {                                                    \
    const u16*   Asrc_ = ((kb_) < 4) ? A1 : A2;                                \
    const float* Wsrc_ = ((kb_) < 4) ? Wa : Wb;                                \
    int ldw_  = ((kb_) < 4) ? ldwa : ldwb;                                     \
    int kloc_ = ((kb_) & 3) * 32;                                              \
    int grow_ = i0 + a_row;                                                    \
    if (grow_ < N) sA = *(const uint4*)(Asrc_ + (size_t)grow_ * 128 + kloc_ + a_q * 8); \
    else           sA = make_uint4(0u, 0u, 0u, 0u);                            \
    const float* wp_ = Wsrc_ + (size_t)w_row * ldw_ + kloc_ + w_half * 16;     \
    sw0 = *(const float4*)(wp_);      sw1 = *(const float4*)(wp_ + 4);         \
    sw2 = *(const float4*)(wp_ + 8);  sw3 = *(const float4*)(wp_ + 12);        \
} while (0)

#define STORE_TILE() do {                                                      \
    *(uint4*)&Al[a_half][a_row][a_col0] = sA;                                  \
    uint4 wv_;                                                                 \
    wv_.x = PK(sw0.x, sw0.y); wv_.y = PK(sw0.z, sw0.w);                        \
    wv_.z = PK(sw1.x, sw1.y); wv_.w = PK(sw1.z, sw1.w);                        \
    *(uint4*)&Wl[w_half][w_row][0] = wv_;                                      \
    wv_.x = PK(sw2.x, sw2.y); wv_.y = PK(sw2.z, sw2.w);                        \
    wv_.z = PK(sw3.x, sw3.y); wv_.w = PK(sw3.z, sw3.w);                        \
    *(uint4*)&Wl[w_half][w_row][8] = wv_;                                      \
} while (0)

template <bool L2N, bool BIAS>
__global__ __launch_bounds__(256, 4) void k_gemm2(
    const u16* __restrict__ A1, const u16* __restrict__ A2,
    const float* __restrict__ Wa, int ldwa,
    const float* __restrict__ Wb, int ldwb,
    const float* __restrict__ bias,
    u16* __restrict__ out, int N)
{
    // [k-half][row][40] bf16; 80 B row stride: 16B-aligned writes, b64 frag
    // reads hit each bank exactly 4x (minimum phases) -> conflict-free.
    __shared__ u16 Al[2][64][40];
    __shared__ u16 Wl[2][128][40];
    int t = threadIdx.x;
    int i0 = blockIdx.x * 64;

    // staging map
    int a_row  = t >> 2;            // 0..63
    int a_q    = t & 3;             // which 8-k chunk
    int a_half = a_q >> 1;          // k-half (0: k<16, 1: k>=16)
    int a_col0 = (a_q & 1) * 8;     // col within half-tile
    int w_row  = t >> 1;            // 0..127 (output feature)
    int w_half = t & 1;             // k-half

    // compute map
    int c16 = t & 15;               // fragment col / A row within wave tile
    int g   = (t >> 4) & 3;         // k-chunk group within lane
    int wid = t >> 6;               // wave id: rows wid*16..+15
    int ar  = wid * 16 + c16;       // A row for this lane's fragment
    int g4  = g * 4;                // bf16 offset of this lane's 4-k chunk

    f32x4 acc[8];
    #pragma unroll
    for (int cb = 0; cb < 8; ++cb) acc[cb] = (f32x4){0.f, 0.f, 0.f, 0.f};

    uint4 sA;
    float4 sw0, sw1, sw2, sw3;

    LOAD_TILE(0);

    union U8 { bf16x8 v; s16x4 h[2]; };

    for (int kb = 0; kb < 8; ++kb) {
        __syncthreads();   // previous tile fully consumed
        STORE_TILE();
        __syncthreads();
        if (kb < 7) LOAD_TILE(kb + 1);  // hide under MFMA below

        U8 af;
        af.h[0] = *(const s16x4*)&Al[0][ar][g4];
        af.h[1] = *(const s16x4*)&Al[1][ar][g4];
        #pragma unroll
        for (int cb = 0; cb < 8; ++cb) {
            U8 bfr;
            int wr = cb * 16 + c16;
            bfr.h[0] = *(const s16x4*)&Wl[0][wr][g4];
            bfr.h[1] = *(const s16x4*)&Wl[1][wr][g4];
            acc[cb] = __builtin_amdgcn_mfma_f32_16x16x32_bf16(af.v, bfr.v, acc[cb], 0, 0, 0);
        }
    }

    // epilogue. D map: col = lane&15 (within cb), row = wid*16 + g*4 + reg.
    float scs[4];
    if (L2N) {
        float s0 = 0.f, s1 = 0.f, s2 = 0.f, s3 = 0.f;
        #pragma unroll
        for (int cb = 0; cb < 8; ++cb) {
            s0 += acc[cb][0] * acc[cb][0];
            s1 += acc[cb][1] * acc[cb][1];
            s2 += acc[cb][2] * acc[cb][2];
            s3 += acc[cb][3] * acc[cb][3];
        }
        #pragma unroll
        for (int off = 1; off < 16; off <<= 1) {
            s0 += __shfl_xor(s0, off);
            s1 += __shfl_xor(s1, off);
            s2 += __shfl_xor(s2, off);
            s3 += __shfl_xor(s3, off);
        }
        scs[0] = 1.0f / fmaxf(sqrtf(s0), L2EPS);
        scs[1] = 1.0f / fmaxf(sqrtf(s1), L2EPS);
        scs[2] = 1.0f / fmaxf(sqrtf(s2), L2EPS);
        scs[3] = 1.0f / fmaxf(sqrtf(s3), L2EPS);
    }
    float bv[8];
    if (BIAS) {
        #pragma unroll
        for (int cb = 0; cb < 8; ++cb) bv[cb] = bias[cb * 16 + c16];
    }
    int rbase = i0 + wid * 16 + g * 4;
    #pragma unroll
    for (int reg = 0; reg < 4; ++reg) {
        int grow = rbase + reg;
        if (grow >= N) continue;
        #pragma unroll
        for (int cb = 0; cb < 8; ++cb) {
            float xv = acc[cb][reg];
            if (L2N) xv *= scs[reg];
            if (BIAS) xv += bv[cb];
            float r = (xv >= 0.f) ? xv : NEG_SLOPE * xv;
            out[(size_t)grow * 128 + cb * 16 + c16] = f2bf(r);
        }
    }
}

// ---------------- pool: chunked partial sums over sorted batch (bf16 in) ----------------
#define POOL_ROWS 128
__global__ void k_pool(const u16* __restrict__ h3, const int* __restrict__ batch,
                       float* __restrict__ pooled, int N) {
    int f = threadIdx.x;  // 0..127
    int base = blockIdx.x * POOL_ROWS;
    if (base >= N) return;
    int end = min(base + POOL_ROWS, N);
    float acc = 0.f;
    int cur = batch[base];
    for (int i = base; i < end; ++i) {
        int g = batch[i];
        if (g != cur) {
            atomicAdd(&pooled[cur * 128 + f], acc);
            acc = 0.f; cur = g;
        }
        acc += bf2f(h3[(size_t)i * 128 + f]);
    }
    atomicAdd(&pooled[cur * 128 + f], acc);
}

__global__ void k_fc3(const float* __restrict__ pooled, const float* __restrict__ W,
                      const float* __restrict__ b, float* __restrict__ out) {
    int g = blockIdx.x, f = threadIdx.x;
    __shared__ float prow[128];
    __shared__ float red[128];
    prow[f] = pooled[g * 128 + f];
    __syncthreads();
    float acc = b[f];
    #pragma unroll 8
    for (int k = 0; k < 128; ++k) acc += prow[k] * W[f * 128 + k];
    float v = (acc >= 0.f) ? acc : NEG_SLOPE * acc;
    red[f] = v * v;
    __syncthreads();
    for (int o = 64; o > 0; o >>= 1) {
        if (f < o) red[f] += red[f + o];
        __syncthreads();
    }
    float sc = 1.0f / fmaxf(sqrtf(red[0]), L2EPS);
    out[g * 128 + f] = v * sc;
}

// ---------------- launch ----------------
extern "C" void kernel_launch(void* const* d_in, const int* in_sizes, int n_in,
                              void* d_out, int out_size, void* d_ws, size_t ws_size,
                              hipStream_t stream) {
    const float* x    = (const float*)d_in[0];
    const int*   ei   = (const int*)d_in[1];
    const int*   batch= (const int*)d_in[2];
    const float* W1l  = (const float*)d_in[3];
    const float* W1r  = (const float*)d_in[4];
    const float* W2l  = (const float*)d_in[5];
    const float* W2r  = (const float*)d_in[6];
    const float* fc1W = (const float*)d_in[7];
    const float* fc1b = (const float*)d_in[8];
    const float* fc2W = (const float*)d_in[9];
    const float* fc2b = (const float*)d_in[10];
    const float* fc3W = (const float*)d_in[11];
    const float* fc3b = (const float*)d_in[12];

    int N = in_sizes[0] / 128;
    int E = in_sizes[1] / 2;
    int G = out_size / 128;
    float* out = (float*)d_out;

    char* ws = (char*)d_ws;
    size_t off = 0;
    auto alloc = [&](size_t bytes) -> void* {
        void* p = ws + off;
        off = (off + bytes + 255) & ~(size_t)255;
        return p;
    };
    u16* xp     = (u16*)alloc((size_t)N * 128 * 2);  // x_pre, later reused as h3
    u16* mean   = (u16*)alloc((size_t)N * 128 * 2);
    u16* h      = (u16*)alloc((size_t)N * 128 * 2);  // h, later h2
    u16* h1     = (u16*)alloc((size_t)N * 128 * 2);
    float* pooled = (float*)alloc((size_t)G * 128 * 4);
    int* deg    = (int*)alloc((size_t)N * 4);
    int* rs     = (int*)alloc((size_t)(N + 1) * 4);
    int* cursor = (int*)alloc((size_t)N * 4);
    int* csr    = (int*)alloc((size_t)E * 4);
    int* bsum   = (int*)alloc(64 * 4);
    (void)ws_size; (void)n_in;

    hipMemsetAsync(deg, 0, (size_t)N * 4, stream);
    hipMemsetAsync(pooled, 0, (size_t)G * 128 * 4, stream);

    int nb = (N + 1023) / 1024;
    k_preprocess<<<(N + 3) / 4, 256, 0, stream>>>(x, xp, N);
    k_deg<<<(E + 255) / 256, 256, 0, stream>>>(ei, deg, E);
    k_scan_part<<<nb, 1024, 0, stream>>>(deg, rs, bsum, N);
    k_scan_bsum<<<1, 64, 0, stream>>>(bsum, rs, nb, N);
    k_scan_add<<<(N + 255) / 256, 256, 0, stream>>>(rs, cursor, bsum, N);
    k_fill<<<(E + 255) / 256, 256, 0, stream>>>(ei, cursor, csr, E);

    int gb = (N + 63) / 64;
    // conv1 + fc1
    k_agg<<<(N + 3) / 4, 256, 0, stream>>>(xp, csr, rs, mean, N);
    k_gemm2<true, false><<<gb, 256, 0, stream>>>(
        mean, xp, W1l, 128, W1r, 128, nullptr, h, N);
    k_gemm2<false, true><<<gb, 256, 0, stream>>>(
        h, xp, fc1W, 256, fc1W + 128, 256, fc1b, h1, N);

    // conv2 + fc2 (h2 -> h buffer, h3 -> xp buffer)
    k_agg<<<(N + 3) / 4, 256, 0, stream>>>(h1, csr, rs, mean, N);
    k_gemm2<true, false><<<gb, 256, 0, stream>>>(
        mean, h1, W2l, 128, W2r, 128, nullptr, h, N);
    k_gemm2<false, true><<<gb, 256, 0, stream>>>(
        h, h1, fc2W, 256, fc2W + 128, 256, fc2b, xp, N);

    // pool + head
    k_pool<<<(N + POOL_ROWS - 1) / POOL_ROWS, 128, 0, stream>>>(xp, batch, pooled, N);
    k_fc3<<<G, 128, 0, stream>>>(pooled, fc3W, fc3b, out);
}

// Round 11
// 315.738 us; speedup vs baseline: 1.7146x; 1.0371x over previous
//
#include <hip/hip_runtime.h>
#include <hip/hip_bf16.h>

// GraphSAGE forward: N=50000 nodes, E=600000 edges, D=H=128, G=128 graphs.
// R8:  bf16 MFMA GEMM + bf16 intermediates (378us).
// R10: multi-block scan + 4-stream agg (327us). Top-5 now harness ws-poison.
// R11: (a) weights pre-converted to bf16 once (kills 16 f2bf/thread/kb in
//      staging); (b) conv+fc fused per layer: h lives in LDS (hT), never HBM.

#define NEG_SLOPE 0.01f
#define L2EPS 1e-12f

typedef unsigned short u16;
typedef short bf16x8 __attribute__((ext_vector_type(8)));
typedef short s16x4  __attribute__((ext_vector_type(4)));
typedef float f32x4  __attribute__((ext_vector_type(4)));

__device__ __forceinline__ float bf_lo(unsigned int u) {
    union { unsigned int i; float f; } v; v.i = u << 16; return v.f;
}
__device__ __forceinline__ float bf_hi(unsigned int u) {
    union { unsigned int i; float f; } v; v.i = u & 0xffff0000u; return v.f;
}
__device__ __forceinline__ u16 f2bf(float f) {
    union { float f; unsigned int i; } v; v.f = f;
    unsigned int r = v.i + 0x7fffu + ((v.i >> 16) & 1u);
    return (u16)(r >> 16);
}
__device__ __forceinline__ float bf2f(u16 u) {
    union { unsigned int i; float f; } v; v.i = ((unsigned int)u) << 16; return v.f;
}

// ---------------- preprocess: row-normalize x, write bf16 ----------------
__global__ void k_preprocess(const float* __restrict__ x, u16* __restrict__ xp, int N) {
    int node = blockIdx.x * 4 + (threadIdx.x >> 6);
    int lane = threadIdx.x & 63;
    if (node >= N) return;
    float2 v = ((const float2*)x)[(size_t)node * 64 + lane];
    float s = v.x + v.y;
    #pragma unroll
    for (int off = 32; off > 0; off >>= 1) s += __shfl_xor(s, off);
    float rinv = (s == 0.0f) ? 0.0f : 1.0f / s;
    unsigned int lo = f2bf(v.x * rinv), hi = f2bf(v.y * rinv);
    ((unsigned int*)xp)[(size_t)node * 64 + lane] = lo | (hi << 16);
}

// ---------------- weight preconversion: 6 matrices f32 -> bf16 ----------------
// wbf layout: [0]=W1l(16384) [16384]=W1r [32768]=W2l [49152]=W2r
//             [65536]=fc1W(32768) [98304]=fc2W(32768)   (131072 elems total)
__global__ void k_wconv(const float* __restrict__ W1l, const float* __restrict__ W1r,
                        const float* __restrict__ W2l, const float* __restrict__ W2r,
                        const float* __restrict__ f1,  const float* __restrict__ f2,
                        u16* __restrict__ wbf) {
    int i = blockIdx.x * 256 + threadIdx.x;   // quad index
    if (i >= 32768) return;
    int e = i * 4;
    const float* src; int off;
    if (e < 65536) {
        int m = e >> 14; off = e & 16383;
        src = (m == 0) ? W1l : (m == 1) ? W1r : (m == 2) ? W2l : W2r;
    } else {
        int m = (e - 65536) >> 15; off = (e - 65536) & 32767;
        src = (m == 0) ? f1 : f2;
    }
    float4 v = *(const float4*)(src + off);
    uint2 o;
    o.x = (unsigned int)f2bf(v.x) | ((unsigned int)f2bf(v.y) << 16);
    o.y = (unsigned int)f2bf(v.z) | ((unsigned int)f2bf(v.w) << 16);
    *(uint2*)(wbf + e) = o;
}

// ---------------- CSR build ----------------
__global__ void k_deg(const int* __restrict__ ei, int* __restrict__ deg, int E) {
    int e = blockIdx.x * blockDim.x + threadIdx.x;
    if (e >= E) return;
    atomicAdd(&deg[ei[E + e]], 1);
}

__global__ void k_scan_part(const int* __restrict__ deg, int* __restrict__ rs,
                            int* __restrict__ bsum, int N) {
    __shared__ int wsum[16];
    int t = threadIdx.x;
    int lane = t & 63, w = t >> 6;
    int i = blockIdx.x * 1024 + t;
    int v = (i < N) ? deg[i] : 0;
    int s = v;
    #pragma unroll
    for (int off = 1; off < 64; off <<= 1) {
        int u = __shfl_up(s, off);
        if (lane >= off) s += u;
    }
    if (lane == 63) wsum[w] = s;
    __syncthreads();
    if (w == 0) {
        int x = (lane < 16) ? wsum[lane] : 0;
        #pragma unroll
        for (int off = 1; off < 16; off <<= 1) {
            int u = __shfl_up(x, off);
            if (lane >= off) x += u;
        }
        if (lane < 16) wsum[lane] = x;
    }
    __syncthreads();
    int wexcl = (w == 0) ? 0 : wsum[w - 1];
    if (i < N) rs[i] = wexcl + s - v;
    if (t == 1023) bsum[blockIdx.x] = wexcl + s;
}

__global__ void k_scan_bsum(int* __restrict__ bsum, int* __restrict__ rs,
                            int nb, int N) {
    int lane = threadIdx.x;
    int v = (lane < nb) ? bsum[lane] : 0;
    int s = v;
    #pragma unroll
    for (int off = 1; off < 64; off <<= 1) {
        int u = __shfl_up(s, off);
        if (lane >= off) s += u;
    }
    if (lane < nb) bsum[lane] = s - v;
    if (lane == nb - 1) rs[N] = s;
}

__global__ void k_scan_add(int* __restrict__ rs, int* __restrict__ cursor,
                           const int* __restrict__ bsum, int N) {
    int i = blockIdx.x * 256 + threadIdx.x;
    if (i >= N) return;
    int v = rs[i] + bsum[i >> 10];
    rs[i] = v;
    cursor[i] = v;
}

__global__ void k_fill(const int* __restrict__ ei, int* __restrict__ cursor,
                       int* __restrict__ csr, int E) {
    int e = blockIdx.x * blockDim.x + threadIdx.x;
    if (e >= E) return;
    int src = ei[e];
    int dst = ei[E + e];
    int pos = atomicAdd(&cursor[dst], 1);
    csr[pos] = src;
}

// ---------------- mean aggregation: 4 edge streams x 2-deep, uint4 gathers ----------------
__global__ void k_agg(const u16* __restrict__ feat, const int* __restrict__ csr,
                      const int* __restrict__ rs, u16* __restrict__ mean, int N) {
    int node = blockIdx.x * 4 + (threadIdx.x >> 6);
    int lane = threadIdx.x & 63;
    if (node >= N) return;
    int beg = rs[node], end = rs[node + 1];
    int d = end - beg;
    int q   = lane >> 4;
    int sub = lane & 15;
    const uint4* fp = (const uint4*)feat;
    float4 aA0 = {0.f,0.f,0.f,0.f}, aB0 = {0.f,0.f,0.f,0.f};
    float4 aA1 = {0.f,0.f,0.f,0.f}, aB1 = {0.f,0.f,0.f,0.f};
    int p = beg + q;
    for (; p + 4 < end; p += 8) {
        int s0 = csr[p], s1 = csr[p + 4];
        uint4 v0 = fp[(size_t)s0 * 16 + sub];
        uint4 v1 = fp[(size_t)s1 * 16 + sub];
        aA0.x += bf_lo(v0.x); aA0.y += bf_hi(v0.x);
        aA0.z += bf_lo(v0.y); aA0.w += bf_hi(v0.y);
        aB0.x += bf_lo(v0.z); aB0.y += bf_hi(v0.z);
        aB0.z += bf_lo(v0.w); aB0.w += bf_hi(v0.w);
        aA1.x += bf_lo(v1.x); aA1.y += bf_hi(v1.x);
        aA1.z += bf_lo(v1.y); aA1.w += bf_hi(v1.y);
        aB1.x += bf_lo(v1.z); aB1.y += bf_hi(v1.z);
        aB1.z += bf_lo(v1.w); aB1.w += bf_hi(v1.w);
    }
    if (p < end) {
        int s0 = csr[p];
        uint4 v0 = fp[(size_t)s0 * 16 + sub];
        aA0.x += bf_lo(v0.x); aA0.y += bf_hi(v0.x);
        aA0.z += bf_lo(v0.y); aA0.w += bf_hi(v0.y);
        aB0.x += bf_lo(v0.z); aB0.y += bf_hi(v0.z);
        aB0.z += bf_lo(v0.w); aB0.w += bf_hi(v0.w);
    }
    aA0.x += aA1.x; aA0.y += aA1.y; aA0.z += aA1.z; aA0.w += aA1.w;
    aB0.x += aB1.x; aB0.y += aB1.y; aB0.z += aB1.z; aB0.w += aB1.w;
    #pragma unroll
    for (int off = 16; off <= 32; off <<= 1) {
        aA0.x += __shfl_xor(aA0.x, off); aA0.y += __shfl_xor(aA0.y, off);
        aA0.z += __shfl_xor(aA0.z, off); aA0.w += __shfl_xor(aA0.w, off);
        aB0.x += __shfl_xor(aB0.x, off); aB0.y += __shfl_xor(aB0.y, off);
        aB0.z += __shfl_xor(aB0.z, off); aB0.w += __shfl_xor(aB0.w, off);
    }
    if (q == 0) {
        float inv = (d > 0) ? (1.0f / (float)d) : 0.0f;
        uint4 o;
        o.x = (unsigned int)f2bf(aA0.x * inv) | ((unsigned int)f2bf(aA0.y * inv) << 16);
        o.y = (unsigned int)f2bf(aA0.z * inv) | ((unsigned int)f2bf(aA0.w * inv) << 16);
        o.z = (unsigned int)f2bf(aB0.x * inv) | ((unsigned int)f2bf(aB0.y * inv) << 16);
        o.w = (unsigned int)f2bf(aB0.z * inv) | ((unsigned int)f2bf(aB0.w * inv) << 16);
        ((uint4*)mean)[(size_t)node * 16 + sub] = o;
    }
}

// ---------------- fused layer: out = leaky([h | Ax] @ Wf.T + b),
//                  h = leaky(l2norm(Am @ Wl.T + Ax @ Wr.T))  (all bf16 MFMA)
// BM=64, 256 threads = 4 waves; wave w owns rows w*16..+15, all 128 cols.
// All weights pre-converted bf16. h lives in LDS (hT), never touches HBM.

#define LOAD_T1(kb_) do {                                                      \
    const u16* As_ = ((kb_) < 4) ? Am : Ax;                                    \
    const u16* Ws_ = ((kb_) < 4) ? Wlb : Wrb;                                  \
    int kl_ = ((kb_) & 3) * 32;                                                \
    int gr_ = i0 + a_row;                                                      \
    if (gr_ < N) sA = *(const uint4*)(As_ + (size_t)gr_ * 128 + kl_ + a_q * 8);\
    else         sA = make_uint4(0u, 0u, 0u, 0u);                              \
    const u16* wp_ = Ws_ + (size_t)w_row * 128 + kl_ + w_half * 16;            \
    sw0 = *(const uint4*)(wp_);  sw1 = *(const uint4*)(wp_ + 8);               \
} while (0)

#define LOAD_T2(kb_) do {                                                      \
    int kl_ = ((kb_) & 3) * 32;                                                \
    if ((kb_) >= 4) {                                                          \
        int gr_ = i0 + a_row;                                                  \
        if (gr_ < N) sA = *(const uint4*)(Ax + (size_t)gr_ * 128 + kl_ + a_q * 8); \
        else         sA = make_uint4(0u, 0u, 0u, 0u);                          \
    }                                                                          \
    int ko_ = kl_ + (((kb_) >= 4) ? 128 : 0);                                  \
    const u16* wp_ = Wfb + (size_t)w_row * 256 + ko_ + w_half * 16;            \
    sw0 = *(const uint4*)(wp_);  sw1 = *(const uint4*)(wp_ + 8);               \
} while (0)

#define STORE_A() do { *(uint4*)&Al[a_half][a_row][a_col0] = sA; } while (0)
#define STORE_W() do {                                                         \
    *(uint4*)&Wl[w_half][w_row][0] = sw0;                                      \
    *(uint4*)&Wl[w_half][w_row][8] = sw1;                                      \
} while (0)

__global__ __launch_bounds__(256, 3) void k_layer(
    const u16* __restrict__ Am, const u16* __restrict__ Ax,
    const u16* __restrict__ Wlb, const u16* __restrict__ Wrb,
    const u16* __restrict__ Wfb, const float* __restrict__ bias,
    u16* __restrict__ out, int N)
{
    __shared__ u16 Al[2][64][40];    // A staging: [k-half][row][16+pad]
    __shared__ u16 Wl[2][128][40];   // W staging
    __shared__ u16 hT[64][136];      // h tile (272 B stride: aligned b64 reads)
    int t = threadIdx.x;
    int i0 = blockIdx.x * 64;

    // staging map
    int a_row  = t >> 2;
    int a_q    = t & 3;
    int a_half = a_q >> 1;
    int a_col0 = (a_q & 1) * 8;
    int w_row  = t >> 1;
    int w_half = t & 1;

    // compute map
    int c16 = t & 15;
    int g   = (t >> 4) & 3;
    int wid = t >> 6;
    int ar  = wid * 16 + c16;
    int g4  = g * 4;

    f32x4 acc[8];
    #pragma unroll
    for (int cb = 0; cb < 8; ++cb) acc[cb] = (f32x4){0.f, 0.f, 0.f, 0.f};

    uint4 sA, sw0, sw1;
    union U8 { bf16x8 v; s16x4 h[2]; };

    // ---- phase 1: conv GEMM ----
    LOAD_T1(0);
    for (int kb = 0; kb < 8; ++kb) {
        __syncthreads();
        STORE_A(); STORE_W();
        __syncthreads();
        if (kb < 7) LOAD_T1(kb + 1);

        U8 af;
        af.h[0] = *(const s16x4*)&Al[0][ar][g4];
        af.h[1] = *(const s16x4*)&Al[1][ar][g4];
        #pragma unroll
        for (int cb = 0; cb < 8; ++cb) {
            U8 bfr;
            int wr = cb * 16 + c16;
            bfr.h[0] = *(const s16x4*)&Wl[0][wr][g4];
            bfr.h[1] = *(const s16x4*)&Wl[1][wr][g4];
            acc[cb] = __builtin_amdgcn_mfma_f32_16x16x32_bf16(af.v, bfr.v, acc[cb], 0, 0, 0);
        }
    }

    // ---- epilogue 1: l2norm + leaky -> hT (LDS) ----
    {
        float s0 = 0.f, s1 = 0.f, s2 = 0.f, s3 = 0.f;
        #pragma unroll
        for (int cb = 0; cb < 8; ++cb) {
            s0 += acc[cb][0] * acc[cb][0];
            s1 += acc[cb][1] * acc[cb][1];
            s2 += acc[cb][2] * acc[cb][2];
            s3 += acc[cb][3] * acc[cb][3];
        }
        #pragma unroll
        for (int off = 1; off < 16; off <<= 1) {
            s0 += __shfl_xor(s0, off);
            s1 += __shfl_xor(s1, off);
            s2 += __shfl_xor(s2, off);
            s3 += __shfl_xor(s3, off);
        }
        float scs[4];
        scs[0] = 1.0f / fmaxf(sqrtf(s0), L2EPS);
        scs[1] = 1.0f / fmaxf(sqrtf(s1), L2EPS);
        scs[2] = 1.0f / fmaxf(sqrtf(s2), L2EPS);
        scs[3] = 1.0f / fmaxf(sqrtf(s3), L2EPS);
        #pragma unroll
        for (int reg = 0; reg < 4; ++reg) {
            int rl = wid * 16 + g * 4 + reg;
            #pragma unroll
            for (int cb = 0; cb < 8; ++cb) {
                float xv = acc[cb][reg] * scs[reg];
                float r = (xv >= 0.f) ? xv : NEG_SLOPE * xv;
                hT[rl][cb * 16 + c16] = f2bf(r);
            }
        }
    }

    // reset accumulators for phase 2
    #pragma unroll
    for (int cb = 0; cb < 8; ++cb) acc[cb] = (f32x4){0.f, 0.f, 0.f, 0.f};

    // ---- phase 2: fc GEMM ([h | Ax] @ Wf.T) ----
    LOAD_T2(0);
    for (int kb = 0; kb < 8; ++kb) {
        __syncthreads();   // kb==0: also orders hT writes before reads below
        if (kb >= 4) STORE_A();
        STORE_W();
        __syncthreads();
        if (kb < 7) LOAD_T2(kb + 1);

        U8 af;
        if (kb < 4) {
            af.h[0] = *(const s16x4*)&hT[ar][kb * 32 + g4];
            af.h[1] = *(const s16x4*)&hT[ar][kb * 32 + 16 + g4];
        } else {
            af.h[0] = *(const s16x4*)&Al[0][ar][g4];
            af.h[1] = *(const s16x4*)&Al[1][ar][g4];
        }
        #pragma unroll
        for (int cb = 0; cb < 8; ++cb) {
            U8 bfr;
            int wr = cb * 16 + c16;
            bfr.h[0] = *(const s16x4*)&Wl[0][wr][g4];
            bfr.h[1] = *(const s16x4*)&Wl[1][wr][g4];
            acc[cb] = __builtin_amdgcn_mfma_f32_16x16x32_bf16(af.v, bfr.v, acc[cb], 0, 0, 0);
        }
    }

    // ---- epilogue 2: bias + leaky -> out (bf16, global) ----
    float bv[8];
    #pragma unroll
    for (int cb = 0; cb < 8; ++cb) bv[cb] = bias[cb * 16 + c16];
    int rbase = i0 + wid * 16 + g * 4;
    #pragma unroll
    for (int reg = 0; reg < 4; ++reg) {
        int grow = rbase + reg;
        if (grow >= N) continue;
        #pragma unroll
        for (int cb = 0; cb < 8; ++cb) {
            float xv = acc[cb][reg] + bv[cb];
            float r = (xv >= 0.f) ? xv : NEG_SLOPE * xv;
            out[(size_t)grow * 128 + cb * 16 + c16] = f2bf(r);
        }
    }
}

// ---------------- pool: chunked partial sums over sorted batch (bf16 in) ----------------
#define POOL_ROWS 128
__global__ void k_pool(const u16* __restrict__ h3, const int* __restrict__ batch,
                       float* __restrict__ pooled, int N) {
    int f = threadIdx.x;
    int base = blockIdx.x * POOL_ROWS;
    if (base >= N) return;
    int end = min(base + POOL_ROWS, N);
    float acc = 0.f;
    int cur = batch[base];
    for (int i = base; i < end; ++i) {
        int g = batch[i];
        if (g != cur) {
            atomicAdd(&pooled[cur * 128 + f], acc);
            acc = 0.f; cur = g;
        }
        acc += bf2f(h3[(size_t)i * 128 + f]);
    }
    atomicAdd(&pooled[cur * 128 + f], acc);
}

__global__ void k_fc3(const float* __restrict__ pooled, const float* __restrict__ W,
                      const float* __restrict__ b, float* __restrict__ out) {
    int g = blockIdx.x, f = threadIdx.x;
    __shared__ float prow[128];
    __shared__ float red[128];
    prow[f] = pooled[g * 128 + f];
    __syncthreads();
    float acc = b[f];
    #pragma unroll 8
    for (int k = 0; k < 128; ++k) acc += prow[k] * W[f * 128 + k];
    float v = (acc >= 0.f) ? acc : NEG_SLOPE * acc;
    red[f] = v * v;
    __syncthreads();
    for (int o = 64; o > 0; o >>= 1) {
        if (f < o) red[f] += red[f + o];
        __syncthreads();
    }
    float sc = 1.0f / fmaxf(sqrtf(red[0]), L2EPS);
    out[g * 128 + f] = v * sc;
}

// ---------------- launch ----------------
extern "C" void kernel_launch(void* const* d_in, const int* in_sizes, int n_in,
                              void* d_out, int out_size, void* d_ws, size_t ws_size,
                              hipStream_t stream) {
    const float* x    = (const float*)d_in[0];
    const int*   ei   = (const int*)d_in[1];
    const int*   batch= (const int*)d_in[2];
    const float* W1l  = (const float*)d_in[3];
    const float* W1r  = (const float*)d_in[4];
    const float* W2l  = (const float*)d_in[5];
    const float* W2r  = (const float*)d_in[6];
    const float* fc1W = (const float*)d_in[7];
    const float* fc1b = (const float*)d_in[8];
    const float* fc2W = (const float*)d_in[9];
    const float* fc2b = (const float*)d_in[10];
    const float* fc3W = (const float*)d_in[11];
    const float* fc3b = (const float*)d_in[12];

    int N = in_sizes[0] / 128;
    int E = in_sizes[1] / 2;
    int G = out_size / 128;
    float* out = (float*)d_out;

    char* ws = (char*)d_ws;
    size_t off = 0;
    auto alloc = [&](size_t bytes) -> void* {
        void* p = ws + off;
        off = (off + bytes + 255) & ~(size_t)255;
        return p;
    };
    u16* xp     = (u16*)alloc((size_t)N * 128 * 2);  // x_pre, later reused as h3
    u16* mean   = (u16*)alloc((size_t)N * 128 * 2);
    u16* h1     = (u16*)alloc((size_t)N * 128 * 2);
    u16* wbf    = (u16*)alloc(131072 * 2);           // all weights, bf16
    float* pooled = (float*)alloc((size_t)G * 128 * 4);
    int* deg    = (int*)alloc((size_t)N * 4);
    int* rs     = (int*)alloc((size_t)(N + 1) * 4);
    int* cursor = (int*)alloc((size_t)N * 4);
    int* csr    = (int*)alloc((size_t)E * 4);
    int* bsum   = (int*)alloc(64 * 4);
    (void)ws_size; (void)n_in;

    hipMemsetAsync(deg, 0, (size_t)N * 4, stream);
    hipMemsetAsync(pooled, 0, (size_t)G * 128 * 4, stream);

    int nb = (N + 1023) / 1024;
    k_preprocess<<<(N + 3) / 4, 256, 0, stream>>>(x, xp, N);
    k_wconv<<<128, 256, 0, stream>>>(W1l, W1r, W2l, W2r, fc1W, fc2W, wbf);
    k_deg<<<(E + 255) / 256, 256, 0, stream>>>(ei, deg, E);
    k_scan_part<<<nb, 1024, 0, stream>>>(deg, rs, bsum, N);
    k_scan_bsum<<<1, 64, 0, stream>>>(bsum, rs, nb, N);
    k_scan_add<<<(N + 255) / 256, 256, 0, stream>>>(rs, cursor, bsum, N);
    k_fill<<<(E + 255) / 256, 256, 0, stream>>>(ei, cursor, csr, E);

    int gb = (N + 63) / 64;
    // layer 1: agg(xp) -> h -> h1 (fused conv1+fc1)
    k_agg<<<(N + 3) / 4, 256, 0, stream>>>(xp, csr, rs, mean, N);
    k_layer<<<gb, 256, 0, stream>>>(
        mean, xp, wbf, wbf + 16384, wbf + 65536, fc1b, h1, N);

    // layer 2: agg(h1) -> h2 -> h3 (fused conv2+fc2); h3 -> xp buffer
    k_agg<<<(N + 3) / 4, 256, 0, stream>>>(h1, csr, rs, mean, N);
    k_layer<<<gb, 256, 0, stream>>>(
        mean, h1, wbf + 32768, wbf + 49152, wbf + 98304, fc2b, xp, N);

    // pool + head
    k_pool<<<(N + POOL_ROWS - 1) / POOL_ROWS, 128, 0, stream>>>(xp, batch, pooled, N);
    k_fc3<<<G, 128, 0, stream>>>(pooled, fc3W, fc3b, out);
}